// Round 1
// baseline (2005.230 us; speedup 1.0000x reference)
//
#include <hip/hip_runtime.h>
#include <hip/hip_bf16.h>

#define N_USERS 100000
#define N_ITEMS 50000
#define N_TOTAL 150000
#define IN_DIM 768
#define BRANCH 64
#define N_EDGES 2097152
#define BATCH 4096
#define NUM_CAND 128
#define NEG 16
#define TEMP 0.1f
#define D2 128

// ---------------- CSR build ----------------

__global__ __launch_bounds__(256) void hist_kernel(const int* __restrict__ rows,
                                                   int* __restrict__ counts) {
    int i = blockIdx.x * blockDim.x + threadIdx.x;
    int stride = gridDim.x * blockDim.x;
    for (; i < N_EDGES; i += stride) atomicAdd(&counts[rows[i]], 1);
}

// single-block in-place exclusive scan of counts -> offsets; also writes cursor copy
__global__ __launch_bounds__(256) void scan_kernel(int* __restrict__ offs,
                                                   int* __restrict__ cur) {
    __shared__ int sums[256];
    int t = threadIdx.x;
    const int CH = (N_TOTAL + 255) / 256;  // 586
    int s0 = t * CH;
    int s1 = s0 + CH; if (s1 > N_TOTAL) s1 = N_TOTAL;
    int loc = 0;
    for (int i = s0; i < s1; ++i) loc += offs[i];
    sums[t] = loc;
    __syncthreads();
    if (t == 0) {
        int run = 0;
        for (int i = 0; i < 256; ++i) { int c = sums[i]; sums[i] = run; run += c; }
    }
    __syncthreads();
    int run = sums[t];
    for (int i = s0; i < s1; ++i) {
        int c = offs[i];
        offs[i] = run;
        cur[i] = run;
        run += c;
    }
    if (t == 255) offs[N_TOTAL] = run;  // == N_EDGES
}

__global__ __launch_bounds__(256) void scatter_kernel(const int* __restrict__ rows,
                                                      const int* __restrict__ cols,
                                                      const float* __restrict__ vals,
                                                      int* __restrict__ cur,
                                                      int* __restrict__ col_s,
                                                      float* __restrict__ val_s) {
    int i = blockIdx.x * blockDim.x + threadIdx.x;
    int stride = gridDim.x * blockDim.x;
    for (; i < N_EDGES; i += stride) {
        int r = rows[i];
        int p = atomicAdd(&cur[r], 1);
        col_s[p] = cols[i];
        val_s[p] = vals[i];
    }
}

// ---------------- GCN ----------------

__global__ __launch_bounds__(256) void init_ego_kernel(const float* __restrict__ uw,
                                                       const float* __restrict__ iw,
                                                       float* __restrict__ ego,
                                                       float* __restrict__ acc) {
    long i = (long)blockIdx.x * blockDim.x + threadIdx.x;  // float4 index
    const long n4 = (long)N_TOTAL * BRANCH / 4;            // 2.4M
    if (i >= n4) return;
    long fi = i * 4;
    const long usz = (long)N_USERS * BRANCH;               // 6.4M, %4==0
    float4 v;
    if (fi < usz) v = *(const float4*)(uw + fi);
    else          v = *(const float4*)(iw + (fi - usz));
    *(float4*)(ego + fi) = v;
    *(float4*)(acc + fi) = v;
}

// one wave per row: out[row] = sum_e val*ego_in[col]; acc[row] += out[row]
__global__ __launch_bounds__(256) void spmv_kernel(const int* __restrict__ offs,
                                                   const int* __restrict__ col_s,
                                                   const float* __restrict__ val_s,
                                                   const float* __restrict__ ego_in,
                                                   float* __restrict__ ego_out,
                                                   float* __restrict__ acc) {
    int wave = (blockIdx.x * 256 + threadIdx.x) >> 6;
    int lane = threadIdx.x & 63;
    if (wave >= N_TOTAL) return;
    int s = offs[wave], e = offs[wave + 1];
    float sum = 0.f;
    for (int i = s; i < e; ++i) {
        float v = val_s[i];
        int c = col_s[i];
        sum += v * ego_in[(long)c * BRANCH + lane];
    }
    long o = (long)wave * BRANCH + lane;
    ego_out[o] = sum;
    acc[o] += sum;
}

// ---------------- semantic GEMM: y = x @ W + b (store raw into sem half) ----------------
// 64 rows x 64 cols per block, K-tile 96, 4x4 micro-tile per thread.

#define BM 64
#define BK 96

__global__ __launch_bounds__(256) void sem_gemm_kernel(const float* __restrict__ user_base,
                                                       const float* __restrict__ item_base,
                                                       const float* __restrict__ W,
                                                       const float* __restrict__ bias,
                                                       float* __restrict__ all_emb) {
    __shared__ float As[BM * BK];   // 24 KB
    __shared__ float Ws[BK * 64];   // 24 KB
    int row0 = blockIdx.x * BM;
    int tid = threadIdx.x;
    int tr = (tid / 16) * 4;   // 0..60
    int tc = (tid % 16) * 4;   // 0..60
    float acc[4][4] = {};

    for (int kt = 0; kt < IN_DIM; kt += BK) {
        // stage A: 64 rows x 96 floats = 1536 float4 / 256 threads = 6 each
        for (int i = 0; i < 6; ++i) {
            int idx = tid + i * 256;       // 0..1535
            int r   = idx / 24;            // 24 float4 per row
            int c4  = idx % 24;
            int gr  = row0 + r;
            const float* src;
            long goff;
            if (gr < N_USERS)      { src = user_base; goff = (long)gr * IN_DIM + kt + c4 * 4; }
            else if (gr < N_TOTAL) { src = item_base; goff = (long)(gr - N_USERS) * IN_DIM + kt + c4 * 4; }
            else                   { src = user_base; goff = kt + c4 * 4; }  // dummy
            float4 v = *(const float4*)(src + goff);
            *(float4*)(As + r * BK + c4 * 4) = v;
        }
        // stage W: 96 x 64 = 1536 float4
        for (int i = 0; i < 6; ++i) {
            int idx = tid + i * 256;
            int r   = idx / 16;
            int c4  = idx % 16;
            float4 v = *(const float4*)(W + (long)(kt + r) * 64 + c4 * 4);
            *(float4*)(Ws + r * 64 + c4 * 4) = v;
        }
        __syncthreads();
        for (int k = 0; k < BK; ++k) {
            float a0 = As[(tr + 0) * BK + k];
            float a1 = As[(tr + 1) * BK + k];
            float a2 = As[(tr + 2) * BK + k];
            float a3 = As[(tr + 3) * BK + k];
            float4 w = *(const float4*)(Ws + k * 64 + tc);
            acc[0][0] += a0 * w.x; acc[0][1] += a0 * w.y; acc[0][2] += a0 * w.z; acc[0][3] += a0 * w.w;
            acc[1][0] += a1 * w.x; acc[1][1] += a1 * w.y; acc[1][2] += a1 * w.z; acc[1][3] += a1 * w.w;
            acc[2][0] += a2 * w.x; acc[2][1] += a2 * w.y; acc[2][2] += a2 * w.z; acc[2][3] += a2 * w.w;
            acc[3][0] += a3 * w.x; acc[3][1] += a3 * w.y; acc[3][2] += a3 * w.z; acc[3][3] += a3 * w.w;
        }
        __syncthreads();
    }

    float4 b = *(const float4*)(bias + tc);
    for (int i = 0; i < 4; ++i) {
        int gr = row0 + tr + i;
        if (gr < N_TOTAL) {
            float4 o;
            o.x = acc[i][0] + b.x;
            o.y = acc[i][1] + b.y;
            o.z = acc[i][2] + b.z;
            o.w = acc[i][3] + b.w;
            *(float4*)(all_emb + (long)gr * D2 + BRANCH + tc) = o;
        }
    }
}

// ---------------- fusion: normalize halves, then joint normalize ----------------

__global__ __launch_bounds__(256) void fuse_kernel(const float* __restrict__ acc,
                                                   float* __restrict__ all_emb) {
    int wave = (blockIdx.x * 256 + threadIdx.x) >> 6;
    int lane = threadIdx.x & 63;
    if (wave >= N_TOTAL) return;

    float c = acc[(long)wave * BRANCH + lane] * 0.25f;
    float cs = c * c;
    #pragma unroll
    for (int off = 1; off < 64; off <<= 1) cs += __shfl_xor(cs, off);
    float cn = c / fmaxf(sqrtf(cs), 1e-12f);

    float s = all_emb[(long)wave * D2 + BRANCH + lane];
    float ss = s * s;
    #pragma unroll
    for (int off = 1; off < 64; off <<= 1) ss += __shfl_xor(ss, off);
    float sn = s / fmaxf(sqrtf(ss), 1e-12f);

    float tt = cn * cn + sn * sn;
    #pragma unroll
    for (int off = 1; off < 64; off <<= 1) tt += __shfl_xor(tt, off);
    float inv = 1.0f / fmaxf(sqrtf(tt), 1e-12f);

    all_emb[(long)wave * D2 + lane]          = cn * inv;
    all_emb[(long)wave * D2 + BRANCH + lane] = sn * inv;
}

// ---------------- batch scoring + top-16 + loss ----------------

__global__ __launch_bounds__(128) void loss_kernel(const float* __restrict__ all_emb,
                                                   const int* __restrict__ uids,
                                                   const int* __restrict__ pos_iids,
                                                   const int* __restrict__ cand_ids,
                                                   float* __restrict__ out) {
    __shared__ __align__(16) float uL[128];
    __shared__ float sc[128];
    __shared__ float redv[128];
    __shared__ int   ridx[128];
    __shared__ float topvals[NEG];

    int b = blockIdx.x;
    int t = threadIdx.x;
    int uid = uids[b];
    int pid = pos_iids[b];
    const float* ib = all_emb + (long)N_USERS * D2;  // item rows

    uL[t] = all_emb[(long)uid * D2 + t];
    __syncthreads();

    // positive logit (dot over 128 dims)
    redv[t] = uL[t] * ib[(long)pid * D2 + t];
    __syncthreads();
    for (int st = 64; st > 0; st >>= 1) {
        if (t < st) redv[t] += redv[t + st];
        __syncthreads();
    }
    float pos_dot = redv[0];

    // candidate scores: thread t <-> candidate t
    int cand = cand_ids[(long)b * NUM_CAND + t];
    if (cand == pid) cand = (cand + 1) % N_ITEMS;
    const float4* cr4 = (const float4*)(ib + (long)cand * D2);
    const float4* u4  = (const float4*)uL;
    float s = 0.f;
    #pragma unroll 8
    for (int k = 0; k < 32; ++k) {
        float4 a = cr4[k];
        float4 u = u4[k];
        s += a.x * u.x + a.y * u.y + a.z * u.z + a.w * u.w;
    }
    sc[t] = s;
    __syncthreads();

    // iterative top-16 (values only; neg_logit == top-k candidate scores)
    for (int it = 0; it < NEG; ++it) {
        redv[t] = sc[t];
        ridx[t] = t;
        __syncthreads();
        for (int st = 64; st > 0; st >>= 1) {
            if (t < st) {
                if (redv[t + st] > redv[t]) { redv[t] = redv[t + st]; ridx[t] = ridx[t + st]; }
            }
            __syncthreads();
        }
        if (t == 0) {
            topvals[it] = redv[0];
            sc[ridx[0]] = -3.0e38f;
        }
        __syncthreads();
    }

    if (t == 0) {
        float pl = pos_dot / TEMP;
        float m = pl;
        #pragma unroll
        for (int i = 0; i < NEG; ++i) m = fmaxf(m, topvals[i] / TEMP);
        float se = __expf(pl - m);
        #pragma unroll
        for (int i = 0; i < NEG; ++i) se += __expf(topvals[i] / TEMP - m);
        float lse = m + __logf(se);
        atomicAdd(out, (lse - pl) * (1.0f / BATCH));
    }
}

// ---------------- launch ----------------

extern "C" void kernel_launch(void* const* d_in, const int* in_sizes, int n_in,
                              void* d_out, int out_size, void* d_ws, size_t ws_size,
                              hipStream_t stream) {
    const float* raw_item_embs = (const float*)d_in[0];   // [50000,768]
    const float* user_sem_base = (const float*)d_in[1];   // [100000,768]
    const float* sem_w         = (const float*)d_in[2];   // [768,64]
    const float* sem_b         = (const float*)d_in[3];   // [64]
    const float* collab_user_w = (const float*)d_in[4];   // [100000,64]
    const float* collab_item_w = (const float*)d_in[5];   // [50000,64]
    const float* adj_vals      = (const float*)d_in[6];   // [2M]
    const int*   adj_rows      = (const int*)d_in[7];
    const int*   adj_cols      = (const int*)d_in[8];
    const int*   uids          = (const int*)d_in[9];
    const int*   pos_iids      = (const int*)d_in[10];
    const int*   cand_ids      = (const int*)d_in[11];
    float* out = (float*)d_out;

    // workspace layout (floats / ints)
    float* all_emb = (float*)d_ws;                         // 150000*128
    float* acc     = all_emb + (long)N_TOTAL * D2;         // 150000*64
    float* egoA    = acc  + (long)N_TOTAL * BRANCH;
    float* egoB    = egoA + (long)N_TOTAL * BRANCH;
    int*   offs    = (int*)(egoB + (long)N_TOTAL * BRANCH);  // N_TOTAL+1
    int*   cur     = offs + (N_TOTAL + 1);
    int*   col_s   = cur + N_TOTAL;                          // N_EDGES
    float* val_s   = (float*)(col_s + N_EDGES);              // N_EDGES

    hipMemsetAsync(offs, 0, (N_TOTAL + 1) * sizeof(int), stream);
    hipMemsetAsync(out, 0, sizeof(float), stream);

    // CSR build
    hist_kernel<<<4096, 256, 0, stream>>>(adj_rows, offs);
    scan_kernel<<<1, 256, 0, stream>>>(offs, cur);
    scatter_kernel<<<4096, 256, 0, stream>>>(adj_rows, adj_cols, adj_vals, cur, col_s, val_s);

    // GCN
    init_ego_kernel<<<(N_TOTAL * BRANCH / 4 + 255) / 256, 256, 0, stream>>>(
        collab_user_w, collab_item_w, egoA, acc);
    const int spmv_blocks = N_TOTAL * 64 / 256;  // 37500
    spmv_kernel<<<spmv_blocks, 256, 0, stream>>>(offs, col_s, val_s, egoA, egoB, acc);
    spmv_kernel<<<spmv_blocks, 256, 0, stream>>>(offs, col_s, val_s, egoB, egoA, acc);
    spmv_kernel<<<spmv_blocks, 256, 0, stream>>>(offs, col_s, val_s, egoA, egoB, acc);

    // semantic branch
    sem_gemm_kernel<<<(N_TOTAL + BM - 1) / BM, 256, 0, stream>>>(
        user_sem_base, raw_item_embs, sem_w, sem_b, all_emb);

    // fusion
    fuse_kernel<<<spmv_blocks, 256, 0, stream>>>(acc, all_emb);

    // loss
    loss_kernel<<<BATCH, 128, 0, stream>>>(all_emb, uids, pos_iids, cand_ids, out);
}

// Round 2
// 1662.317 us; speedup vs baseline: 1.2063x; 1.2063x over previous
//
#include <hip/hip_runtime.h>
#include <hip/hip_bf16.h>

#define N_USERS 100000
#define N_ITEMS 50000
#define N_TOTAL 150000
#define IN_DIM 768
#define BRANCH 64
#define N_EDGES 2097152
#define BATCH 4096
#define NUM_CAND 128
#define NEG 16
#define TEMP 0.1f
#define D2 128

#define SCAN_CHUNK 1024
#define SCAN_BLOCKS ((N_TOTAL + SCAN_CHUNK - 1) / SCAN_CHUNK)  // 147

// ---------------- CSR build ----------------

__global__ __launch_bounds__(256) void hist_kernel(const int* __restrict__ rows,
                                                   int* __restrict__ counts) {
    int i = blockIdx.x * blockDim.x + threadIdx.x;
    int stride = gridDim.x * blockDim.x;
    for (; i < N_EDGES; i += stride) atomicAdd(&counts[rows[i]], 1);
}

// --- parallel scan, 3 stages ---

__global__ __launch_bounds__(256) void scan_partial(const int* __restrict__ counts,
                                                    int* __restrict__ bs) {
    int t = threadIdx.x;
    long fi = ((long)blockIdx.x * 256 + t) * 4;
    int4 v = {0, 0, 0, 0};
    if (fi < N_TOTAL) v = *(const int4*)(counts + fi);  // N_TOTAL % 4 == 0
    int s = v.x + v.y + v.z + v.w;
    #pragma unroll
    for (int off = 1; off < 64; off <<= 1) s += __shfl_xor(s, off);
    __shared__ int wsum[4];
    int lane = t & 63, wid = t >> 6;
    if (lane == 0) wsum[wid] = s;
    __syncthreads();
    if (t == 0) bs[blockIdx.x] = wsum[0] + wsum[1] + wsum[2] + wsum[3];
}

__global__ __launch_bounds__(256) void scan_blocksums(int* __restrict__ bs,
                                                      int* __restrict__ offs) {
    int t = threadIdx.x;
    int x = (t < SCAN_BLOCKS) ? bs[t] : 0;
    int orig = x;
    int lane = t & 63, wid = t >> 6;
    #pragma unroll
    for (int off = 1; off < 64; off <<= 1) {
        int y = __shfl_up(x, off);
        if (lane >= off) x += y;
    }
    __shared__ int wsum[4], woff[4];
    if (lane == 63) wsum[wid] = x;
    __syncthreads();
    if (t == 0) {
        int r = 0;
        for (int i = 0; i < 4; ++i) { woff[i] = r; r += wsum[i]; }
    }
    __syncthreads();
    int incl = x + woff[wid];
    if (t < SCAN_BLOCKS) bs[t] = incl - orig;        // exclusive prefix
    if (t == SCAN_BLOCKS - 1) offs[N_TOTAL] = incl;  // total == N_EDGES
}

__global__ __launch_bounds__(256) void scan_final(const int* __restrict__ bs,
                                                  int* __restrict__ offs,
                                                  int* __restrict__ cur) {
    int t = threadIdx.x;
    long fi = ((long)blockIdx.x * 256 + t) * 4;
    int4 v = {0, 0, 0, 0};
    bool ok = fi < N_TOTAL;
    if (ok) v = *(const int4*)(offs + fi);
    int s = v.x + v.y + v.z + v.w;
    int x = s;
    int lane = t & 63, wid = t >> 6;
    #pragma unroll
    for (int off = 1; off < 64; off <<= 1) {
        int y = __shfl_up(x, off);
        if (lane >= off) x += y;
    }
    __shared__ int wsum[4], woff[4];
    if (lane == 63) wsum[wid] = x;
    __syncthreads();
    if (t == 0) {
        int r = 0;
        for (int i = 0; i < 4; ++i) { woff[i] = r; r += wsum[i]; }
    }
    __syncthreads();
    int excl = (x - s) + woff[wid] + bs[blockIdx.x];
    if (ok) {
        int4 o;
        o.x = excl;
        o.y = o.x + v.x;
        o.z = o.y + v.y;
        o.w = o.z + v.z;
        *(int4*)(offs + fi) = o;
        *(int4*)(cur + fi)  = o;
    }
}

__global__ __launch_bounds__(256) void scatter_kernel(const int* __restrict__ rows,
                                                      const int* __restrict__ cols,
                                                      const float* __restrict__ vals,
                                                      int* __restrict__ cur,
                                                      int* __restrict__ col_s,
                                                      float* __restrict__ val_s) {
    int i = blockIdx.x * blockDim.x + threadIdx.x;
    int stride = gridDim.x * blockDim.x;
    for (; i < N_EDGES; i += stride) {
        int r = rows[i];
        int p = atomicAdd(&cur[r], 1);
        col_s[p] = cols[i];
        val_s[p] = vals[i];
    }
}

// ---------------- GCN ----------------

__global__ __launch_bounds__(256) void init_ego_kernel(const float* __restrict__ uw,
                                                       const float* __restrict__ iw,
                                                       float* __restrict__ ego,
                                                       float* __restrict__ acc) {
    long i = (long)blockIdx.x * blockDim.x + threadIdx.x;  // float4 index
    const long n4 = (long)N_TOTAL * BRANCH / 4;            // 2.4M
    if (i >= n4) return;
    long fi = i * 4;
    const long usz = (long)N_USERS * BRANCH;               // 6.4M, %4==0
    float4 v;
    if (fi < usz) v = *(const float4*)(uw + fi);
    else          v = *(const float4*)(iw + (fi - usz));
    *(float4*)(ego + fi) = v;
    *(float4*)(acc + fi) = v;
}

// one wave per row: out[row] = sum_e val*ego_in[col]; acc[row] += out[row]
__global__ __launch_bounds__(256) void spmv_kernel(const int* __restrict__ offs,
                                                   const int* __restrict__ col_s,
                                                   const float* __restrict__ val_s,
                                                   const float* __restrict__ ego_in,
                                                   float* __restrict__ ego_out,
                                                   float* __restrict__ acc) {
    int wave = (blockIdx.x * 256 + threadIdx.x) >> 6;
    int lane = threadIdx.x & 63;
    if (wave >= N_TOTAL) return;
    int s = offs[wave], e = offs[wave + 1];
    float sum = 0.f;
    for (int i = s; i < e; ++i) {
        float v = val_s[i];
        int c = col_s[i];
        sum += v * ego_in[(long)c * BRANCH + lane];
    }
    long o = (long)wave * BRANCH + lane;
    ego_out[o] = sum;
    acc[o] += sum;
}

// ---------------- semantic GEMM: y = x @ W + b (store raw into sem half) ----------------

#define BM 64
#define BK 96

__global__ __launch_bounds__(256) void sem_gemm_kernel(const float* __restrict__ user_base,
                                                       const float* __restrict__ item_base,
                                                       const float* __restrict__ W,
                                                       const float* __restrict__ bias,
                                                       float* __restrict__ all_emb) {
    __shared__ float As[BM * BK];   // 24 KB
    __shared__ float Ws[BK * 64];   // 24 KB
    int row0 = blockIdx.x * BM;
    int tid = threadIdx.x;
    int tr = (tid / 16) * 4;   // 0..60
    int tc = (tid % 16) * 4;   // 0..60
    float acc[4][4] = {};

    for (int kt = 0; kt < IN_DIM; kt += BK) {
        for (int i = 0; i < 6; ++i) {
            int idx = tid + i * 256;       // 0..1535
            int r   = idx / 24;            // 24 float4 per row
            int c4  = idx % 24;
            int gr  = row0 + r;
            const float* src;
            long goff;
            if (gr < N_USERS)      { src = user_base; goff = (long)gr * IN_DIM + kt + c4 * 4; }
            else if (gr < N_TOTAL) { src = item_base; goff = (long)(gr - N_USERS) * IN_DIM + kt + c4 * 4; }
            else                   { src = user_base; goff = kt + c4 * 4; }  // dummy
            float4 v = *(const float4*)(src + goff);
            *(float4*)(As + r * BK + c4 * 4) = v;
        }
        for (int i = 0; i < 6; ++i) {
            int idx = tid + i * 256;
            int r   = idx / 16;
            int c4  = idx % 16;
            float4 v = *(const float4*)(W + (long)(kt + r) * 64 + c4 * 4);
            *(float4*)(Ws + r * 64 + c4 * 4) = v;
        }
        __syncthreads();
        for (int k = 0; k < BK; ++k) {
            float a0 = As[(tr + 0) * BK + k];
            float a1 = As[(tr + 1) * BK + k];
            float a2 = As[(tr + 2) * BK + k];
            float a3 = As[(tr + 3) * BK + k];
            float4 w = *(const float4*)(Ws + k * 64 + tc);
            acc[0][0] += a0 * w.x; acc[0][1] += a0 * w.y; acc[0][2] += a0 * w.z; acc[0][3] += a0 * w.w;
            acc[1][0] += a1 * w.x; acc[1][1] += a1 * w.y; acc[1][2] += a1 * w.z; acc[1][3] += a1 * w.w;
            acc[2][0] += a2 * w.x; acc[2][1] += a2 * w.y; acc[2][2] += a2 * w.z; acc[2][3] += a2 * w.w;
            acc[3][0] += a3 * w.x; acc[3][1] += a3 * w.y; acc[3][2] += a3 * w.z; acc[3][3] += a3 * w.w;
        }
        __syncthreads();
    }

    float4 b = *(const float4*)(bias + tc);
    for (int i = 0; i < 4; ++i) {
        int gr = row0 + tr + i;
        if (gr < N_TOTAL) {
            float4 o;
            o.x = acc[i][0] + b.x;
            o.y = acc[i][1] + b.y;
            o.z = acc[i][2] + b.z;
            o.w = acc[i][3] + b.w;
            *(float4*)(all_emb + (long)gr * D2 + BRANCH + tc) = o;
        }
    }
}

// ---------------- fusion ----------------

__global__ __launch_bounds__(256) void fuse_kernel(const float* __restrict__ acc,
                                                   float* __restrict__ all_emb) {
    int wave = (blockIdx.x * 256 + threadIdx.x) >> 6;
    int lane = threadIdx.x & 63;
    if (wave >= N_TOTAL) return;

    float c = acc[(long)wave * BRANCH + lane] * 0.25f;
    float cs = c * c;
    #pragma unroll
    for (int off = 1; off < 64; off <<= 1) cs += __shfl_xor(cs, off);
    float cn = c / fmaxf(sqrtf(cs), 1e-12f);

    float s = all_emb[(long)wave * D2 + BRANCH + lane];
    float ss = s * s;
    #pragma unroll
    for (int off = 1; off < 64; off <<= 1) ss += __shfl_xor(ss, off);
    float sn = s / fmaxf(sqrtf(ss), 1e-12f);

    float tt = cn * cn + sn * sn;
    #pragma unroll
    for (int off = 1; off < 64; off <<= 1) tt += __shfl_xor(tt, off);
    float inv = 1.0f / fmaxf(sqrtf(tt), 1e-12f);

    all_emb[(long)wave * D2 + lane]          = cn * inv;
    all_emb[(long)wave * D2 + BRANCH + lane] = sn * inv;
}

// ---------------- batch scoring + top-16 + loss ----------------

__global__ __launch_bounds__(128) void loss_kernel(const float* __restrict__ all_emb,
                                                   const int* __restrict__ uids,
                                                   const int* __restrict__ pos_iids,
                                                   const int* __restrict__ cand_ids,
                                                   float* __restrict__ out) {
    __shared__ __align__(16) float uL[128];
    __shared__ float sc[128];
    __shared__ float redv[128];
    __shared__ int   ridx[128];
    __shared__ float topvals[NEG];

    int b = blockIdx.x;
    int t = threadIdx.x;
    int uid = uids[b];
    int pid = pos_iids[b];
    const float* ib = all_emb + (long)N_USERS * D2;  // item rows

    uL[t] = all_emb[(long)uid * D2 + t];
    __syncthreads();

    redv[t] = uL[t] * ib[(long)pid * D2 + t];
    __syncthreads();
    for (int st = 64; st > 0; st >>= 1) {
        if (t < st) redv[t] += redv[t + st];
        __syncthreads();
    }
    float pos_dot = redv[0];

    int cand = cand_ids[(long)b * NUM_CAND + t];
    if (cand == pid) cand = (cand + 1) % N_ITEMS;
    const float4* cr4 = (const float4*)(ib + (long)cand * D2);
    const float4* u4  = (const float4*)uL;
    float s = 0.f;
    #pragma unroll 8
    for (int k = 0; k < 32; ++k) {
        float4 a = cr4[k];
        float4 u = u4[k];
        s += a.x * u.x + a.y * u.y + a.z * u.z + a.w * u.w;
    }
    sc[t] = s;
    __syncthreads();

    for (int it = 0; it < NEG; ++it) {
        redv[t] = sc[t];
        ridx[t] = t;
        __syncthreads();
        for (int st = 64; st > 0; st >>= 1) {
            if (t < st) {
                if (redv[t + st] > redv[t]) { redv[t] = redv[t + st]; ridx[t] = ridx[t + st]; }
            }
            __syncthreads();
        }
        if (t == 0) {
            topvals[it] = redv[0];
            sc[ridx[0]] = -3.0e38f;
        }
        __syncthreads();
    }

    if (t == 0) {
        float pl = pos_dot / TEMP;
        float m = pl;
        #pragma unroll
        for (int i = 0; i < NEG; ++i) m = fmaxf(m, topvals[i] / TEMP);
        float se = __expf(pl - m);
        #pragma unroll
        for (int i = 0; i < NEG; ++i) se += __expf(topvals[i] / TEMP - m);
        float lse = m + __logf(se);
        atomicAdd(out, (lse - pl) * (1.0f / BATCH));
    }
}

// ---------------- launch ----------------

extern "C" void kernel_launch(void* const* d_in, const int* in_sizes, int n_in,
                              void* d_out, int out_size, void* d_ws, size_t ws_size,
                              hipStream_t stream) {
    const float* raw_item_embs = (const float*)d_in[0];
    const float* user_sem_base = (const float*)d_in[1];
    const float* sem_w         = (const float*)d_in[2];
    const float* sem_b         = (const float*)d_in[3];
    const float* collab_user_w = (const float*)d_in[4];
    const float* collab_item_w = (const float*)d_in[5];
    const float* adj_vals      = (const float*)d_in[6];
    const int*   adj_rows      = (const int*)d_in[7];
    const int*   adj_cols      = (const int*)d_in[8];
    const int*   uids          = (const int*)d_in[9];
    const int*   pos_iids      = (const int*)d_in[10];
    const int*   cand_ids      = (const int*)d_in[11];
    float* out = (float*)d_out;

    float* all_emb = (float*)d_ws;                         // 150000*128
    float* acc     = all_emb + (long)N_TOTAL * D2;         // 150000*64
    float* egoA    = acc  + (long)N_TOTAL * BRANCH;
    float* egoB    = egoA + (long)N_TOTAL * BRANCH;
    int*   offs    = (int*)(egoB + (long)N_TOTAL * BRANCH);  // N_TOTAL+1
    int*   cur     = offs + (N_TOTAL + 4);                   // keep 16B alignment
    int*   col_s   = cur + N_TOTAL;                          // N_EDGES
    float* val_s   = (float*)(col_s + N_EDGES);              // N_EDGES
    int*   bsums   = (int*)(val_s + N_EDGES);                // SCAN_BLOCKS

    hipMemsetAsync(offs, 0, (N_TOTAL + 1) * sizeof(int), stream);
    hipMemsetAsync(out, 0, sizeof(float), stream);

    // CSR build
    hist_kernel<<<4096, 256, 0, stream>>>(adj_rows, offs);
    scan_partial<<<SCAN_BLOCKS, 256, 0, stream>>>(offs, bsums);
    scan_blocksums<<<1, 256, 0, stream>>>(bsums, offs);
    scan_final<<<SCAN_BLOCKS, 256, 0, stream>>>(bsums, offs, cur);
    scatter_kernel<<<4096, 256, 0, stream>>>(adj_rows, adj_cols, adj_vals, cur, col_s, val_s);

    // GCN
    init_ego_kernel<<<(N_TOTAL * BRANCH / 4 + 255) / 256, 256, 0, stream>>>(
        collab_user_w, collab_item_w, egoA, acc);
    const int spmv_blocks = N_TOTAL * 64 / 256;  // 37500
    spmv_kernel<<<spmv_blocks, 256, 0, stream>>>(offs, col_s, val_s, egoA, egoB, acc);
    spmv_kernel<<<spmv_blocks, 256, 0, stream>>>(offs, col_s, val_s, egoB, egoA, acc);
    spmv_kernel<<<spmv_blocks, 256, 0, stream>>>(offs, col_s, val_s, egoA, egoB, acc);

    // semantic branch
    sem_gemm_kernel<<<(N_TOTAL + BM - 1) / BM, 256, 0, stream>>>(
        user_sem_base, raw_item_embs, sem_w, sem_b, all_emb);

    // fusion
    fuse_kernel<<<spmv_blocks, 256, 0, stream>>>(acc, all_emb);

    // loss
    loss_kernel<<<BATCH, 128, 0, stream>>>(all_emb, uids, pos_iids, cand_ids, out);
}

// Round 3
// 1526.741 us; speedup vs baseline: 1.3134x; 1.0888x over previous
//
#include <hip/hip_runtime.h>
#include <hip/hip_bf16.h>

#define N_USERS 100000
#define N_ITEMS 50000
#define N_TOTAL 150000
#define IN_DIM 768
#define BRANCH 64
#define N_EDGES 2097152
#define BATCH 4096
#define NUM_CAND 128
#define NEG 16
#define TEMP 0.1f
#define D2 128

#define SCAN_CHUNK 1024
#define SCAN_BLOCKS ((N_TOTAL + SCAN_CHUNK - 1) / SCAN_CHUNK)  // 147

typedef short short8 __attribute__((ext_vector_type(8)));
typedef float f32x4 __attribute__((ext_vector_type(4)));

__device__ __forceinline__ unsigned short f2bf(float f) {
    unsigned int u = __builtin_bit_cast(unsigned int, f);
    u += 0x7fffu + ((u >> 16) & 1u);   // round-to-nearest-even
    return (unsigned short)(u >> 16);
}

// ---------------- CSR build ----------------

__global__ __launch_bounds__(256) void hist_kernel(const int* __restrict__ rows,
                                                   int* __restrict__ counts) {
    int i = blockIdx.x * blockDim.x + threadIdx.x;
    int stride = gridDim.x * blockDim.x;
    for (; i < N_EDGES; i += stride) atomicAdd(&counts[rows[i]], 1);
}

__global__ __launch_bounds__(256) void scan_partial(const int* __restrict__ counts,
                                                    int* __restrict__ bs) {
    int t = threadIdx.x;
    long fi = ((long)blockIdx.x * 256 + t) * 4;
    int4 v = {0, 0, 0, 0};
    if (fi < N_TOTAL) v = *(const int4*)(counts + fi);  // N_TOTAL % 4 == 0
    int s = v.x + v.y + v.z + v.w;
    #pragma unroll
    for (int off = 1; off < 64; off <<= 1) s += __shfl_xor(s, off);
    __shared__ int wsum[4];
    int lane = t & 63, wid = t >> 6;
    if (lane == 0) wsum[wid] = s;
    __syncthreads();
    if (t == 0) bs[blockIdx.x] = wsum[0] + wsum[1] + wsum[2] + wsum[3];
}

__global__ __launch_bounds__(256) void scan_blocksums(int* __restrict__ bs,
                                                      int* __restrict__ offs) {
    int t = threadIdx.x;
    int x = (t < SCAN_BLOCKS) ? bs[t] : 0;
    int orig = x;
    int lane = t & 63, wid = t >> 6;
    #pragma unroll
    for (int off = 1; off < 64; off <<= 1) {
        int y = __shfl_up(x, off);
        if (lane >= off) x += y;
    }
    __shared__ int wsum[4], woff[4];
    if (lane == 63) wsum[wid] = x;
    __syncthreads();
    if (t == 0) {
        int r = 0;
        for (int i = 0; i < 4; ++i) { woff[i] = r; r += wsum[i]; }
    }
    __syncthreads();
    int incl = x + woff[wid];
    if (t < SCAN_BLOCKS) bs[t] = incl - orig;        // exclusive prefix
    if (t == SCAN_BLOCKS - 1) offs[N_TOTAL] = incl;  // total == N_EDGES
}

__global__ __launch_bounds__(256) void scan_final(const int* __restrict__ bs,
                                                  int* __restrict__ offs,
                                                  int* __restrict__ cur) {
    int t = threadIdx.x;
    long fi = ((long)blockIdx.x * 256 + t) * 4;
    int4 v = {0, 0, 0, 0};
    bool ok = fi < N_TOTAL;
    if (ok) v = *(const int4*)(offs + fi);
    int s = v.x + v.y + v.z + v.w;
    int x = s;
    int lane = t & 63, wid = t >> 6;
    #pragma unroll
    for (int off = 1; off < 64; off <<= 1) {
        int y = __shfl_up(x, off);
        if (lane >= off) x += y;
    }
    __shared__ int wsum[4], woff[4];
    if (lane == 63) wsum[wid] = x;
    __syncthreads();
    if (t == 0) {
        int r = 0;
        for (int i = 0; i < 4; ++i) { woff[i] = r; r += wsum[i]; }
    }
    __syncthreads();
    int excl = (x - s) + woff[wid] + bs[blockIdx.x];
    if (ok) {
        int4 o;
        o.x = excl;
        o.y = o.x + v.x;
        o.z = o.y + v.y;
        o.w = o.z + v.z;
        *(int4*)(offs + fi) = o;
        *(int4*)(cur + fi)  = o;
    }
}

__global__ __launch_bounds__(256) void scatter_kernel(const int* __restrict__ rows,
                                                      const int* __restrict__ cols,
                                                      const float* __restrict__ vals,
                                                      int* __restrict__ cur,
                                                      int* __restrict__ col_s,
                                                      float* __restrict__ val_s) {
    int i = blockIdx.x * blockDim.x + threadIdx.x;
    int stride = gridDim.x * blockDim.x;
    for (; i < N_EDGES; i += stride) {
        int r = rows[i];
        int p = atomicAdd(&cur[r], 1);
        col_s[p] = cols[i];
        val_s[p] = vals[i];
    }
}

// ---------------- GCN ----------------

__global__ __launch_bounds__(256) void init_ego_kernel(const float* __restrict__ uw,
                                                       const float* __restrict__ iw,
                                                       float* __restrict__ ego,
                                                       float* __restrict__ acc) {
    long i = (long)blockIdx.x * blockDim.x + threadIdx.x;  // float4 index
    const long n4 = (long)N_TOTAL * BRANCH / 4;
    if (i >= n4) return;
    long fi = i * 4;
    const long usz = (long)N_USERS * BRANCH;
    float4 v;
    if (fi < usz) v = *(const float4*)(uw + fi);
    else          v = *(const float4*)(iw + (fi - usz));
    *(float4*)(ego + fi) = v;
    *(float4*)(acc + fi) = v;
}

__global__ __launch_bounds__(256) void spmv_kernel(const int* __restrict__ offs,
                                                   const int* __restrict__ col_s,
                                                   const float* __restrict__ val_s,
                                                   const float* __restrict__ ego_in,
                                                   float* __restrict__ ego_out,
                                                   float* __restrict__ acc) {
    int wave = (blockIdx.x * 256 + threadIdx.x) >> 6;
    int lane = threadIdx.x & 63;
    if (wave >= N_TOTAL) return;
    int s = offs[wave], e = offs[wave + 1];
    float sum = 0.f;
    for (int i = s; i < e; ++i) {
        float v = val_s[i];
        int c = col_s[i];
        sum += v * ego_in[(long)c * BRANCH + lane];
    }
    long o = (long)wave * BRANCH + lane;
    ego_out[o] = sum;
    acc[o] += sum;
}

// ---------------- semantic branch: bf16 MFMA GEMM ----------------

__global__ __launch_bounds__(256) void wt_prep(const float* __restrict__ W,
                                               unsigned short* __restrict__ gWt) {
    int idx = blockIdx.x * 256 + threadIdx.x;  // over 64*768
    if (idx >= 64 * IN_DIM) return;
    int n = idx / IN_DIM, k = idx % IN_DIM;
    gWt[idx] = f2bf(W[(long)k * 64 + n]);
}

#define GROWS 128
#define GK 32
#define LSTR 40   // padded LDS row stride (bf16 elems): 80 B, 16B-aligned, conflict-free b128 reads

__global__ __launch_bounds__(256) void sem_gemm_mfma(const float* __restrict__ user_base,
                                                     const float* __restrict__ item_base,
                                                     const unsigned short* __restrict__ gWt,
                                                     const float* __restrict__ bias,
                                                     float* __restrict__ all_emb) {
    __shared__ unsigned short Asl[GROWS * LSTR];  // [row][k] 10 KB
    __shared__ unsigned short Wsl[64 * LSTR];     // [n][k]   5 KB

    const int tid  = threadIdx.x;
    const int row0 = blockIdx.x * GROWS;
    const int wv   = tid >> 6;
    const int lane = tid & 63;
    const int l15  = lane & 15;
    const int quad = lane >> 4;

    const int s_r = tid >> 3;        // 0..31
    const int s_c = (tid & 7) * 4;   // 0..28

    f32x4 acc[2][4];
    #pragma unroll
    for (int r = 0; r < 2; ++r)
        #pragma unroll
        for (int c = 0; c < 4; ++c)
            acc[r][c] = (f32x4){0.f, 0.f, 0.f, 0.f};

    const int wt_n  = tid >> 2;
    const int wt_c8 = (tid & 3) * 8;

    for (int kt = 0; kt < IN_DIM; kt += GK) {
        // stage A (fp32 -> bf16)
        #pragma unroll
        for (int i = 0; i < 4; ++i) {
            int r = s_r + i * 32;
            int gr = row0 + r;
            if (gr >= N_TOTAL) gr = 0;
            const float* src = (gr < N_USERS) ? (user_base + (long)gr * IN_DIM)
                                              : (item_base + (long)(gr - N_USERS) * IN_DIM);
            float4 v = *(const float4*)(src + kt + s_c);
            unsigned short* d = &Asl[r * LSTR + s_c];
            d[0] = f2bf(v.x); d[1] = f2bf(v.y); d[2] = f2bf(v.z); d[3] = f2bf(v.w);
        }
        // stage Wt (already bf16): 16 B per thread
        {
            uint4 v = *(const uint4*)(gWt + (long)wt_n * IN_DIM + kt + wt_c8);
            *(uint4*)(&Wsl[wt_n * LSTR + wt_c8]) = v;
        }
        __syncthreads();

        const int arow = wv * 32 + l15;
        short8 a0 = *(const short8*)(&Asl[arow * LSTR + quad * 8]);
        short8 a1 = *(const short8*)(&Asl[(arow + 16) * LSTR + quad * 8]);
        short8 b[4];
        #pragma unroll
        for (int c = 0; c < 4; ++c)
            b[c] = *(const short8*)(&Wsl[(c * 16 + l15) * LSTR + quad * 8]);
        #pragma unroll
        for (int c = 0; c < 4; ++c) {
            acc[0][c] = __builtin_amdgcn_mfma_f32_16x16x32_bf16(a0, b[c], acc[0][c], 0, 0, 0);
            acc[1][c] = __builtin_amdgcn_mfma_f32_16x16x32_bf16(a1, b[c], acc[1][c], 0, 0, 0);
        }
        __syncthreads();
    }

    // epilogue: D[row][col] -> all_emb[row][64+col] + bias
    #pragma unroll
    for (int r = 0; r < 2; ++r) {
        #pragma unroll
        for (int c = 0; c < 4; ++c) {
            int col = c * 16 + l15;
            float bv = bias[col];
            #pragma unroll
            for (int i = 0; i < 4; ++i) {
                int gr = row0 + wv * 32 + r * 16 + quad * 4 + i;
                if (gr < N_TOTAL)
                    all_emb[(long)gr * D2 + BRANCH + col] = acc[r][c][i] + bv;
            }
        }
    }
}

// ---------------- fusion ----------------

__global__ __launch_bounds__(256) void fuse_kernel(const float* __restrict__ acc,
                                                   float* __restrict__ all_emb) {
    int wave = (blockIdx.x * 256 + threadIdx.x) >> 6;
    int lane = threadIdx.x & 63;
    if (wave >= N_TOTAL) return;

    float c = acc[(long)wave * BRANCH + lane] * 0.25f;
    float cs = c * c;
    #pragma unroll
    for (int off = 1; off < 64; off <<= 1) cs += __shfl_xor(cs, off);
    float cn = c / fmaxf(sqrtf(cs), 1e-12f);

    float s = all_emb[(long)wave * D2 + BRANCH + lane];
    float ss = s * s;
    #pragma unroll
    for (int off = 1; off < 64; off <<= 1) ss += __shfl_xor(ss, off);
    float sn = s / fmaxf(sqrtf(ss), 1e-12f);

    float tt = cn * cn + sn * sn;
    #pragma unroll
    for (int off = 1; off < 64; off <<= 1) tt += __shfl_xor(tt, off);
    float inv = 1.0f / fmaxf(sqrtf(tt), 1e-12f);

    all_emb[(long)wave * D2 + lane]          = cn * inv;
    all_emb[(long)wave * D2 + BRANCH + lane] = sn * inv;
}

// ---------------- batch scoring + top-16 + loss ----------------

__global__ __launch_bounds__(128) void loss_kernel(const float* __restrict__ all_emb,
                                                   const int* __restrict__ uids,
                                                   const int* __restrict__ pos_iids,
                                                   const int* __restrict__ cand_ids,
                                                   float* __restrict__ out) {
    __shared__ __align__(16) float uL[128];
    __shared__ float sc[128];
    __shared__ float redv[128];
    __shared__ int   ridx[128];
    __shared__ float topvals[NEG];

    int b = blockIdx.x;
    int t = threadIdx.x;
    int uid = uids[b];
    int pid = pos_iids[b];
    const float* ib = all_emb + (long)N_USERS * D2;

    uL[t] = all_emb[(long)uid * D2 + t];
    __syncthreads();

    redv[t] = uL[t] * ib[(long)pid * D2 + t];
    __syncthreads();
    for (int st = 64; st > 0; st >>= 1) {
        if (t < st) redv[t] += redv[t + st];
        __syncthreads();
    }
    float pos_dot = redv[0];

    int cand = cand_ids[(long)b * NUM_CAND + t];
    if (cand == pid) cand = (cand + 1) % N_ITEMS;
    const float4* cr4 = (const float4*)(ib + (long)cand * D2);
    const float4* u4  = (const float4*)uL;
    float s = 0.f;
    #pragma unroll 8
    for (int k = 0; k < 32; ++k) {
        float4 a = cr4[k];
        float4 u = u4[k];
        s += a.x * u.x + a.y * u.y + a.z * u.z + a.w * u.w;
    }
    sc[t] = s;
    __syncthreads();

    for (int it = 0; it < NEG; ++it) {
        redv[t] = sc[t];
        ridx[t] = t;
        __syncthreads();
        for (int st = 64; st > 0; st >>= 1) {
            if (t < st) {
                if (redv[t + st] > redv[t]) { redv[t] = redv[t + st]; ridx[t] = ridx[t + st]; }
            }
            __syncthreads();
        }
        if (t == 0) {
            topvals[it] = redv[0];
            sc[ridx[0]] = -3.0e38f;
        }
        __syncthreads();
    }

    if (t == 0) {
        float pl = pos_dot / TEMP;
        float m = pl;
        #pragma unroll
        for (int i = 0; i < NEG; ++i) m = fmaxf(m, topvals[i] / TEMP);
        float se = __expf(pl - m);
        #pragma unroll
        for (int i = 0; i < NEG; ++i) se += __expf(topvals[i] / TEMP - m);
        float lse = m + __logf(se);
        atomicAdd(out, (lse - pl) * (1.0f / BATCH));
    }
}

// ---------------- launch ----------------

extern "C" void kernel_launch(void* const* d_in, const int* in_sizes, int n_in,
                              void* d_out, int out_size, void* d_ws, size_t ws_size,
                              hipStream_t stream) {
    const float* raw_item_embs = (const float*)d_in[0];
    const float* user_sem_base = (const float*)d_in[1];
    const float* sem_w         = (const float*)d_in[2];
    const float* sem_b         = (const float*)d_in[3];
    const float* collab_user_w = (const float*)d_in[4];
    const float* collab_item_w = (const float*)d_in[5];
    const float* adj_vals      = (const float*)d_in[6];
    const int*   adj_rows      = (const int*)d_in[7];
    const int*   adj_cols      = (const int*)d_in[8];
    const int*   uids          = (const int*)d_in[9];
    const int*   pos_iids      = (const int*)d_in[10];
    const int*   cand_ids      = (const int*)d_in[11];
    float* out = (float*)d_out;

    float* all_emb = (float*)d_ws;                           // 150000*128
    float* acc     = all_emb + (long)N_TOTAL * D2;           // 150000*64
    float* egoA    = acc  + (long)N_TOTAL * BRANCH;
    float* egoB    = egoA + (long)N_TOTAL * BRANCH;
    int*   offs    = (int*)(egoB + (long)N_TOTAL * BRANCH);  // N_TOTAL+1
    int*   cur     = offs + (N_TOTAL + 4);                   // keep 16B alignment
    int*   col_s   = cur + N_TOTAL;                          // N_EDGES
    float* val_s   = (float*)(col_s + N_EDGES);              // N_EDGES
    int*   bsums   = (int*)(val_s + N_EDGES);                // SCAN_BLOCKS (pad to 256)
    unsigned short* gWt = (unsigned short*)(bsums + 256);    // 64*768 bf16

    hipMemsetAsync(offs, 0, (N_TOTAL + 1) * sizeof(int), stream);
    hipMemsetAsync(out, 0, sizeof(float), stream);

    // CSR build
    hist_kernel<<<4096, 256, 0, stream>>>(adj_rows, offs);
    scan_partial<<<SCAN_BLOCKS, 256, 0, stream>>>(offs, bsums);
    scan_blocksums<<<1, 256, 0, stream>>>(bsums, offs);
    scan_final<<<SCAN_BLOCKS, 256, 0, stream>>>(bsums, offs, cur);
    scatter_kernel<<<4096, 256, 0, stream>>>(adj_rows, adj_cols, adj_vals, cur, col_s, val_s);

    // GCN
    init_ego_kernel<<<(N_TOTAL * BRANCH / 4 + 255) / 256, 256, 0, stream>>>(
        collab_user_w, collab_item_w, egoA, acc);
    const int spmv_blocks = N_TOTAL * 64 / 256;  // 37500
    spmv_kernel<<<spmv_blocks, 256, 0, stream>>>(offs, col_s, val_s, egoA, egoB, acc);
    spmv_kernel<<<spmv_blocks, 256, 0, stream>>>(offs, col_s, val_s, egoB, egoA, acc);
    spmv_kernel<<<spmv_blocks, 256, 0, stream>>>(offs, col_s, val_s, egoA, egoB, acc);

    // semantic branch (bf16 MFMA)
    wt_prep<<<(64 * IN_DIM + 255) / 256, 256, 0, stream>>>(sem_w, gWt);
    sem_gemm_mfma<<<(N_TOTAL + GROWS - 1) / GROWS, 256, 0, stream>>>(
        user_sem_base, raw_item_embs, gWt, sem_b, all_emb);

    // fusion
    fuse_kernel<<<spmv_blocks, 256, 0, stream>>>(acc, all_emb);

    // loss
    loss_kernel<<<BATCH, 128, 0, stream>>>(all_emb, uids, pos_iids, cand_ids, out);
}